// Round 4
// baseline (401.685 us; speedup 1.0000x reference)
//
#include <hip/hip_runtime.h>
#include <math.h>

#define HID 128
#define HEADS 8
#define CDIM 16

typedef short bf8 __attribute__((ext_vector_type(8)));
typedef float f32x4 __attribute__((ext_vector_type(4)));

__device__ __forceinline__ unsigned short f2bf(float f) {
    unsigned u = __float_as_uint(f);
    unsigned r = (u + 0x7fffu + ((u >> 16) & 1u)) >> 16;
    return (unsigned short)r;
}
__device__ __forceinline__ float bf2f(unsigned short u) {
    return __uint_as_float(((unsigned)u) << 16);
}

// ---- P0: Wt[j][k] = bf16(W[k][j]) + zero deg ---------------------------
__global__ __launch_bounds__(256) void k_tw(const float* __restrict__ W,
                                            unsigned short* __restrict__ Wt,
                                            int* __restrict__ deg, int N) {
    int idx = blockIdx.x * 256 + threadIdx.x;   // 512 blocks = 131072 threads
    if (idx < HID * HID) {
        int j = idx >> 7, k = idx & 127;
        Wt[idx] = f2bf(W[k * HID + j]);
    }
    if (idx < N) deg[idx] = 0;
}

// ---- P1: exact per-node in-degree via global atomics (L2-resident) ------
__global__ __launch_bounds__(256) void k_deg(const int* __restrict__ dst,
                                             int* __restrict__ deg, int E) {
    int i = blockIdx.x * 256 + threadIdx.x;
    int stride = gridDim.x * 256;
    for (int e = i; e < E; e += stride) atomicAdd(&deg[dst[e]], 1);
}

// ---- P2: 2-level exclusive scan over deg[N] -----------------------------
__global__ __launch_bounds__(256) void kscanA(const int* __restrict__ in,
                                              int* __restrict__ tmp,
                                              int* __restrict__ bsum, int M) {
    __shared__ int lds[256];
    int t = threadIdx.x;
    int base = blockIdx.x * 1024 + t * 4;
    int v[4];
#pragma unroll
    for (int i = 0; i < 4; i++) {
        int idx = base + i;
        v[i] = (idx < M) ? in[idx] : 0;
    }
    int s = v[0] + v[1] + v[2] + v[3];
    lds[t] = s;
    __syncthreads();
    for (int off = 1; off < 256; off <<= 1) {
        int xv = (t >= off) ? lds[t - off] : 0;
        __syncthreads();
        lds[t] += xv;
        __syncthreads();
    }
    int run = (t > 0) ? lds[t - 1] : 0;
#pragma unroll
    for (int i = 0; i < 4; i++) {
        int idx = base + i;
        if (idx < M) tmp[idx] = run;
        run += v[i];
    }
    if (t == 255) bsum[blockIdx.x] = lds[255];
}

__global__ __launch_bounds__(128) void kscanB(const int* __restrict__ bsum,
                                              int* __restrict__ bscan, int nb,
                                              const float* __restrict__ w_edge,
                                              const float* __restrict__ att_edge,
                                              float* __restrict__ w_e) {
    __shared__ int lds[128];
    int t = threadIdx.x;
    if (t < HEADS) {
        float s = 0.f;
        for (int c = 0; c < CDIM; c++) s += w_edge[t * CDIM + c] * att_edge[t * CDIM + c];
        w_e[t] = s;
    }
    lds[t] = (t < nb) ? bsum[t] : 0;
    __syncthreads();
    for (int off = 1; off < 128; off <<= 1) {
        int xv = (t >= off) ? lds[t - off] : 0;
        __syncthreads();
        lds[t] += xv;
        __syncthreads();
    }
    bscan[t] = (t > 0) ? lds[t - 1] : 0;
}

// ---- MID: heterogeneous blocks: [0,gemmBlocks) = GEMM, rest = scatter ---
// GEMM: h = x@W via MFMA (bf16 in, fp32 acc) + a_src/a_dst epilogue.
// Scatter: single pass, final position via backward-fill atomic on deg.
__global__ __launch_bounds__(256) void k_mid(const float* __restrict__ x,
                                             const unsigned short* __restrict__ Wt,
                                             const float* __restrict__ att_src,
                                             const float* __restrict__ att_dst,
                                             unsigned short* __restrict__ hbf,
                                             float* __restrict__ a_src,
                                             float* __restrict__ a_dst,
                                             const int* __restrict__ src,
                                             const int* __restrict__ dst,
                                             const float* __restrict__ eattr,
                                             const int* __restrict__ tmp,
                                             const int* __restrict__ bscan,
                                             int* __restrict__ deg,
                                             int2* __restrict__ erec,
                                             int N, int E, int gemmBlocks,
                                             int scatBlocks) {
    if ((int)blockIdx.x >= gemmBlocks) {
        // ---- scatter body ----
        int bid = blockIdx.x - gemmBlocks;
        int i = bid * 256 + threadIdx.x;
        int stride = scatBlocks * 256;
        for (int e = i; e < E; e += stride) {
            int d = dst[e];
            int old = atomicAdd(&deg[d], -1);
            int pos = tmp[d] + bscan[d >> 10] + old - 1;
            erec[pos] = make_int2(src[e], __float_as_int(eattr[e]));
        }
        return;
    }
    // ---- GEMM body ----
    int tid = threadIdx.x;
    int wv = tid >> 6, lane = tid & 63;
    int nloc = lane & 15, q = lane >> 4;
    int node = blockIdx.x * 64 + wv * 16 + nloc;
    int nc = min(node, N - 1);
    const float* xp = x + (size_t)nc * HID + q * 8;
    const unsigned short* wp = Wt + nloc * HID + q * 8; // A row j = jt*16 + nloc
    f32x4 acc[8];
#pragma unroll
    for (int i = 0; i < 8; i++) acc[i] = (f32x4){0.f, 0.f, 0.f, 0.f};
#pragma unroll
    for (int ch = 0; ch < 4; ch++) {
        float4 xv0 = *(const float4*)(xp + ch * 32);
        float4 xv1 = *(const float4*)(xp + ch * 32 + 4);
        bf8 bfrag;
        bfrag[0] = (short)f2bf(xv0.x); bfrag[1] = (short)f2bf(xv0.y);
        bfrag[2] = (short)f2bf(xv0.z); bfrag[3] = (short)f2bf(xv0.w);
        bfrag[4] = (short)f2bf(xv1.x); bfrag[5] = (short)f2bf(xv1.y);
        bfrag[6] = (short)f2bf(xv1.z); bfrag[7] = (short)f2bf(xv1.w);
#pragma unroll
        for (int jt = 0; jt < 8; jt++) {
            bf8 afrag = *(const bf8*)(wp + (size_t)jt * 16 * HID + ch * 32);
            acc[jt] = __builtin_amdgcn_mfma_f32_16x16x32_bf16(afrag, bfrag, acc[jt], 0, 0, 0);
        }
    }
    bool ok = node < N;
    size_t hb = (size_t)nc * HID;
#pragma unroll
    for (int jt = 0; jt < 8; jt++) {
        int j0 = jt * 16 + q * 4;
        float4 as4 = *(const float4*)(att_src + j0);
        float4 ad4 = *(const float4*)(att_dst + j0);
        f32x4 a = acc[jt];
        float ps = a[0] * as4.x + a[1] * as4.y + a[2] * as4.z + a[3] * as4.w;
        float pd = a[0] * ad4.x + a[1] * ad4.y + a[2] * ad4.z + a[3] * ad4.w;
        ps += __shfl_xor(ps, 16, 64); ps += __shfl_xor(ps, 32, 64);
        pd += __shfl_xor(pd, 16, 64); pd += __shfl_xor(pd, 32, 64);
        if (ok) {
            ushort4 hv;
            hv.x = f2bf(a[0]); hv.y = f2bf(a[1]); hv.z = f2bf(a[2]); hv.w = f2bf(a[3]);
            *(ushort4*)(hbf + hb + j0) = hv;
            if (q == 0) {
                a_src[(size_t)node * 8 + jt] = ps;
                a_dst[(size_t)node * 8 + jt] = pd;
            }
        }
    }
}

// ---- K6 v4: per-node fused attn+aggregate+selfloop+LN+ReLU --------------
// Barrier-free, LDS-free. 8 waves/block (512 thr), 1 node/wave. 16-lane
// group owns 2 edges/iteration (6 independent loads in flight for latency
// hiding). Epilogue redistribution via pure shuffles.
__global__ __launch_bounds__(512) void k_node(const int* __restrict__ tmp,
                                              const int* __restrict__ bscan,
                                              const int2* __restrict__ erec,
                                              const float* __restrict__ a_src,
                                              const float* __restrict__ a_dst,
                                              const float* __restrict__ w_e,
                                              const unsigned short* __restrict__ hbf,
                                              const float* __restrict__ x,
                                              const float* __restrict__ bias,
                                              const float* __restrict__ gamma,
                                              const float* __restrict__ beta,
                                              float* __restrict__ out, int N, int E) {
    int wv = threadIdx.x >> 6;
    int lane = threadIdx.x & 63;
    int n = blockIdx.x * 8 + wv;
    if (n >= N) return;
    int r0 = tmp[n] + bscan[n >> 10];
    int r1 = (n + 1 < N) ? (tmp[n + 1] + bscan[(n + 1) >> 10]) : E;
    int sub = lane >> 4;        // which of 4 concurrent edge-pairs
    int colg = lane & 15;       // col group: cols colg*8 .. colg*8+7
    int wh = colg >> 1;         // head of this col group
    float ad_h = a_dst[(size_t)n * 8 + wh];
    float we_h = w_e[wh];

    float acc[8];
#pragma unroll
    for (int j = 0; j < 8; j++) acc[j] = 0.f;
    float wsum = 0.f, suma = 0.f;

    for (int e = r0 + (sub << 1); e < r1; e += 8) {
        int2 rec0 = erec[e];
        bool m1 = (e + 1) < r1;
        int2 rec1 = m1 ? erec[e + 1] : rec0;
        int s0 = rec0.x, s1 = rec1.x;
        float ae0 = __int_as_float(rec0.y);
        float ae1 = __int_as_float(rec1.y);
        bf8 hv0 = *(const bf8*)(hbf + (size_t)s0 * HID + colg * 8);
        bf8 hv1 = *(const bf8*)(hbf + (size_t)s1 * HID + colg * 8);
        float as0 = a_src[(size_t)s0 * 8 + wh];
        float as1 = a_src[(size_t)s1 * 8 + wh];
        float v0 = as0 + ad_h + ae0 * we_h;
        float v1 = as1 + ad_h + ae1 * we_h;
        v0 = v0 > 0.f ? v0 : 0.2f * v0;
        v1 = v1 > 0.f ? v1 : 0.2f * v1;
        float w0 = __expf(v0);
        float w1 = m1 ? __expf(v1) : 0.f;
        wsum += w0 + w1;
        if (colg == 0) suma += ae0 + (m1 ? ae1 : 0.f);
#pragma unroll
        for (int j = 0; j < 8; j++) {
            acc[j] = fmaf(w0, bf2f((unsigned short)hv0[j]), acc[j]);
            acc[j] = fmaf(w1, bf2f((unsigned short)hv1[j]), acc[j]);
        }
    }

    // fold the 4 sub replicas: full per-col sums, per-head denom, attr sum
#pragma unroll
    for (int j = 0; j < 8; j++) {
        acc[j] += __shfl_xor(acc[j], 16, 64);
        acc[j] += __shfl_xor(acc[j], 32, 64);
    }
    wsum += __shfl_xor(wsum, 16, 64);
    wsum += __shfl_xor(wsum, 32, 64);
    suma += __shfl_xor(suma, 16, 64);
    suma += __shfl_xor(suma, 32, 64);

    // redistribute to 2-cols/lane: source lane (sub,colg) offers
    // (acc[2*sub], acc[2*sub+1]) = cols 8*colg+2*sub, +1.
    // dest lane L wants cols 2L,2L+1 -> srcLane = ((L&3)<<4) | (L>>2).
    float accA = sub == 0 ? acc[0] : sub == 1 ? acc[2] : sub == 2 ? acc[4] : acc[6];
    float accB = sub == 0 ? acc[1] : sub == 1 ? acc[3] : sub == 2 ? acc[5] : acc[7];
    int srcL = ((lane & 3) << 4) | (lane >> 2);
    float a0 = __shfl(accA, srcL, 64);
    float a1 = __shfl(accB, srcL, 64);
    int head = lane >> 3;
    float denom = __shfl(wsum, head << 1, 64);  // lane colg=2h, sub=0
    float sa = __shfl(suma, 0, 64);

    // self-loop (fill_value='mean') + softmax finalize
    int deg = r1 - r0;
    float la = sa / fmaxf((float)deg, 1.0f);
    float adh = a_dst[(size_t)n * 8 + head];
    float weh = w_e[head];
    float vs = a_src[(size_t)n * 8 + head] + adh + la * weh;
    vs = vs > 0.f ? vs : 0.2f * vs;
    float exs = __expf(vs);
    size_t bx = (size_t)n * HID;
    ushort2 hs = *(const ushort2*)(hbf + bx + 2 * lane);
    a0 = fmaf(exs, bf2f(hs.x), a0);
    a1 = fmaf(exs, bf2f(hs.y), a1);
    float inv = 1.f / (denom + exs + 1e-16f);

    // residual + LayerNorm + ReLU
    float2 xv = *(const float2*)(x + bx + 2 * lane);
    float2 bv = *(const float2*)(bias + 2 * lane);
    float y0 = a0 * inv + bv.x + xv.x;
    float y1 = a1 * inv + bv.y + xv.y;
    float ss = y0 + y1, sq = y0 * y0 + y1 * y1;
#pragma unroll
    for (int off = 32; off; off >>= 1) {
        ss += __shfl_xor(ss, off, 64);
        sq += __shfl_xor(sq, off, 64);
    }
    float mu = ss * (1.f / 128.f);
    float var = sq * (1.f / 128.f) - mu * mu;
    float r = rsqrtf(fmaxf(var, 0.f) + 1e-5f);
    float2 gv = *(const float2*)(gamma + 2 * lane);
    float2 tv = *(const float2*)(beta + 2 * lane);
    float o0 = (y0 - mu) * r * gv.x + tv.x;
    float o1 = (y1 - mu) * r * gv.y + tv.y;
    float2 ov = make_float2(fmaxf(o0, 0.f), fmaxf(o1, 0.f));
    *(float2*)(out + bx + 2 * lane) = ov;
}

extern "C" void kernel_launch(void* const* d_in, const int* in_sizes, int n_in,
                              void* d_out, int out_size, void* d_ws, size_t ws_size,
                              hipStream_t stream) {
    const float* x        = (const float*)d_in[0];
    const int*   ei       = (const int*)d_in[1];
    const float* eattr    = (const float*)d_in[2];
    const float* W        = (const float*)d_in[3];
    const float* att_src  = (const float*)d_in[4];
    const float* att_dst  = (const float*)d_in[5];
    const float* w_edge   = (const float*)d_in[6];
    const float* att_edge = (const float*)d_in[7];
    const float* bias     = (const float*)d_in[8];
    const float* gamma    = (const float*)d_in[9];
    const float* beta     = (const float*)d_in[10];

    int N = in_sizes[0] / HID;
    int E = in_sizes[2];
    const int* src = ei;
    const int* dst = ei + E;
    float* out = (float*)d_out;

    char* ws = (char*)d_ws;
    size_t off = 0;
    auto alloc = [&](size_t bytes) { char* p = ws + off; off += (bytes + 255) & ~255ull; return p; };
    unsigned short* hbf = (unsigned short*)alloc((size_t)N * HID * 2);
    unsigned short* Wt  = (unsigned short*)alloc((size_t)HID * HID * 2);
    float* a_src   = (float*)alloc((size_t)N * 8 * 4);
    float* a_dst   = (float*)alloc((size_t)N * 8 * 4);
    int2*  erec    = (int2*) alloc((size_t)E * 8);
    int*   deg     = (int*)  alloc((size_t)N * 4);
    int*   tmp     = (int*)  alloc((size_t)N * 4);
    int*   bsum    = (int*)  alloc(128 * 4);
    int*   bscan   = (int*)  alloc(128 * 4);
    float* w_e     = (float*)alloc(8 * 4);

    int nbA = (N + 1023) / 1024;           // 98 scan blocks
    int gemmBlocks = (N + 63) / 64;        // 1563
    int scatBlocks = 1024;

    k_tw<<<512, 256, 0, stream>>>(W, Wt, deg, N);
    k_deg<<<2048, 256, 0, stream>>>(dst, deg, E);
    kscanA<<<nbA, 256, 0, stream>>>(deg, tmp, bsum, N);
    kscanB<<<1, 128, 0, stream>>>(bsum, bscan, nbA, w_edge, att_edge, w_e);
    k_mid<<<gemmBlocks + scatBlocks, 256, 0, stream>>>(
        x, Wt, att_src, att_dst, hbf, a_src, a_dst,
        src, dst, eattr, tmp, bscan, deg, erec, N, E, gemmBlocks, scatBlocks);
    k_node<<<(N + 7) / 8, 512, 0, stream>>>(tmp, bscan, erec, a_src, a_dst, w_e, hbf, x,
                                            bias, gamma, beta, out, N, E);
}

// Round 5
// 364.410 us; speedup vs baseline: 1.1023x; 1.1023x over previous
//
#include <hip/hip_runtime.h>
#include <math.h>

#define HID 128
#define HEADS 8
#define CDIM 16
#define BKT 256      // nodes per fine bucket

typedef short bf8 __attribute__((ext_vector_type(8)));
typedef float f32x4 __attribute__((ext_vector_type(4)));

__device__ __forceinline__ unsigned short f2bf(float f) {
    unsigned u = __float_as_uint(f);
    unsigned r = (u + 0x7fffu + ((u >> 16) & 1u)) >> 16;
    return (unsigned short)r;
}
__device__ __forceinline__ float bf2f(unsigned short u) {
    return __uint_as_float(((unsigned)u) << 16);
}

// ---- P0: Wt[j][k] = bf16(W[k][j]) + zero deg/bcur ----------------------
__global__ __launch_bounds__(256) void k_tw(const float* __restrict__ W,
                                            unsigned short* __restrict__ Wt,
                                            int* __restrict__ deg,
                                            int* __restrict__ bcur,
                                            int N, int nbkt) {
    int idx = blockIdx.x * 256 + threadIdx.x;   // 512 blocks = 131072 threads
    if (idx < HID * HID) {
        int j = idx >> 7, k = idx & 127;
        Wt[idx] = f2bf(W[k * HID + j]);
    }
    if (idx < N) deg[idx] = 0;
    if (idx < nbkt) bcur[idx] = 0;
}

// ---- P1: exact per-node in-degree via global atomics (L2-resident) ------
__global__ __launch_bounds__(256) void k_deg(const int* __restrict__ dst,
                                             int* __restrict__ deg, int E) {
    int i = blockIdx.x * 256 + threadIdx.x;
    int stride = gridDim.x * 256;
    for (int e = i; e < E; e += stride) atomicAdd(&deg[dst[e]], 1);
}

// ---- P2: 2-level exclusive scan over deg[N] -----------------------------
__global__ __launch_bounds__(256) void kscanA(const int* __restrict__ in,
                                              int* __restrict__ tmp,
                                              int* __restrict__ bsum, int M) {
    __shared__ int lds[256];
    int t = threadIdx.x;
    int base = blockIdx.x * 1024 + t * 4;
    int v[4];
#pragma unroll
    for (int i = 0; i < 4; i++) {
        int idx = base + i;
        v[i] = (idx < M) ? in[idx] : 0;
    }
    int s = v[0] + v[1] + v[2] + v[3];
    lds[t] = s;
    __syncthreads();
    for (int off = 1; off < 256; off <<= 1) {
        int xv = (t >= off) ? lds[t - off] : 0;
        __syncthreads();
        lds[t] += xv;
        __syncthreads();
    }
    int run = (t > 0) ? lds[t - 1] : 0;
#pragma unroll
    for (int i = 0; i < 4; i++) {
        int idx = base + i;
        if (idx < M) tmp[idx] = run;
        run += v[i];
    }
    if (t == 255) bsum[blockIdx.x] = lds[255];
}

__global__ __launch_bounds__(128) void kscanB(const int* __restrict__ bsum,
                                              int* __restrict__ bscan, int nb,
                                              const float* __restrict__ w_edge,
                                              const float* __restrict__ att_edge,
                                              float* __restrict__ w_e) {
    __shared__ int lds[128];
    int t = threadIdx.x;
    if (t < HEADS) {
        float s = 0.f;
        for (int c = 0; c < CDIM; c++) s += w_edge[t * CDIM + c] * att_edge[t * CDIM + c];
        w_e[t] = s;
    }
    lds[t] = (t < nb) ? bsum[t] : 0;
    __syncthreads();
    for (int off = 1; off < 128; off <<= 1) {
        int xv = (t >= off) ? lds[t - off] : 0;
        __syncthreads();
        lds[t] += xv;
        __syncthreads();
    }
    bscan[t] = (t > 0) ? lds[t - 1] : 0;
}

// ---- S1: fused hist + chunk-reserve + bucket-local scatter --------------
// Each block histograms its edge slice into 391 coarse buckets (256 nodes),
// reserves one contiguous chunk per bucket via a single global atomicAdd,
// then scatters with LDS cursors -> sequential chunk writes into erec1.
// Record packs bucket-local dst: key = (src<<8) | (d&255).
__global__ __launch_bounds__(256) void k_scat2(const int* __restrict__ src,
                                               const int* __restrict__ dst,
                                               const float* __restrict__ eattr,
                                               const int* __restrict__ tmp,
                                               const int* __restrict__ bscan,
                                               int* __restrict__ bcur,
                                               int2* __restrict__ erec1,
                                               int E, int per, int nbkt) {
    __shared__ int hist[512];
    __shared__ int cur[512];
    int t = threadIdx.x;
    hist[t] = 0; hist[t + 256] = 0;
    __syncthreads();
    int b0 = blockIdx.x * per;
    int b1 = min(b0 + per, E);
    for (int e = b0 + t; e < b1; e += 256)
        atomicAdd(&hist[dst[e] >> 8], 1);
    __syncthreads();
    for (int b = t; b < nbkt; b += 256) {
        int c = hist[b];
        int base = 0;
        if (c) base = atomicAdd(&bcur[b], c);
        int node0 = b << 8;
        cur[b] = tmp[node0] + bscan[node0 >> 10] + base;
    }
    __syncthreads();
    for (int e = b0 + t; e < b1; e += 256) {
        int d = dst[e];
        int pos = atomicAdd(&cur[d >> 8], 1);
        erec1[pos] = make_int2((src[e] << 8) | (d & 255), __float_as_int(eattr[e]));
    }
}

// ---- S2: fine bin within bucket (single pass, cursors from row_ptr) -----
__global__ __launch_bounds__(256) void k_bin2(const int* __restrict__ tmp,
                                              const int* __restrict__ bscan,
                                              const int2* __restrict__ erec1,
                                              int2* __restrict__ erec,
                                              int N, int E, int nbkt) {
    __shared__ int cur2[256];
    int b = blockIdx.x, t = threadIdx.x;
    int node = (b << 8) + t;
    cur2[t] = (node < N) ? (tmp[node] + bscan[node >> 10]) : 0;
    int n0 = b << 8;
    int base = tmp[n0] + bscan[n0 >> 10];
    int n1 = (b + 1) << 8;
    int end = (n1 < N) ? (tmp[n1] + bscan[n1 >> 10]) : E;
    __syncthreads();
    for (int e = base + t; e < end; e += 256) {
        int2 r = erec1[e];
        int pos = atomicAdd(&cur2[r.x & 255], 1);
        erec[pos] = make_int2(r.x >> 8, r.y);
    }
}

// ---- G: h = x@W via MFMA (bf16 in, fp32 acc) + a_src/a_dst epilogue -----
__global__ __launch_bounds__(256) void k_gemm(const float* __restrict__ x,
                                              const unsigned short* __restrict__ Wt,
                                              const float* __restrict__ att_src,
                                              const float* __restrict__ att_dst,
                                              unsigned short* __restrict__ hbf,
                                              float* __restrict__ a_src,
                                              float* __restrict__ a_dst, int N) {
    int tid = threadIdx.x;
    int wv = tid >> 6, lane = tid & 63;
    int nloc = lane & 15, q = lane >> 4;
    int node = blockIdx.x * 64 + wv * 16 + nloc;
    int nc = min(node, N - 1);
    const float* xp = x + (size_t)nc * HID + q * 8;
    const unsigned short* wp = Wt + nloc * HID + q * 8; // A row j = jt*16 + nloc
    f32x4 acc[8];
#pragma unroll
    for (int i = 0; i < 8; i++) acc[i] = (f32x4){0.f, 0.f, 0.f, 0.f};
#pragma unroll
    for (int ch = 0; ch < 4; ch++) {
        float4 xv0 = *(const float4*)(xp + ch * 32);
        float4 xv1 = *(const float4*)(xp + ch * 32 + 4);
        bf8 bfrag;
        bfrag[0] = (short)f2bf(xv0.x); bfrag[1] = (short)f2bf(xv0.y);
        bfrag[2] = (short)f2bf(xv0.z); bfrag[3] = (short)f2bf(xv0.w);
        bfrag[4] = (short)f2bf(xv1.x); bfrag[5] = (short)f2bf(xv1.y);
        bfrag[6] = (short)f2bf(xv1.z); bfrag[7] = (short)f2bf(xv1.w);
#pragma unroll
        for (int jt = 0; jt < 8; jt++) {
            bf8 afrag = *(const bf8*)(wp + (size_t)jt * 16 * HID + ch * 32);
            acc[jt] = __builtin_amdgcn_mfma_f32_16x16x32_bf16(afrag, bfrag, acc[jt], 0, 0, 0);
        }
    }
    bool ok = node < N;
    size_t hb = (size_t)nc * HID;
#pragma unroll
    for (int jt = 0; jt < 8; jt++) {
        int j0 = jt * 16 + q * 4;
        float4 as4 = *(const float4*)(att_src + j0);
        float4 ad4 = *(const float4*)(att_dst + j0);
        f32x4 a = acc[jt];
        float ps = a[0] * as4.x + a[1] * as4.y + a[2] * as4.z + a[3] * as4.w;
        float pd = a[0] * ad4.x + a[1] * ad4.y + a[2] * ad4.z + a[3] * ad4.w;
        ps += __shfl_xor(ps, 16, 64); ps += __shfl_xor(ps, 32, 64);
        pd += __shfl_xor(pd, 16, 64); pd += __shfl_xor(pd, 32, 64);
        if (ok) {
            ushort4 hv;
            hv.x = f2bf(a[0]); hv.y = f2bf(a[1]); hv.z = f2bf(a[2]); hv.w = f2bf(a[3]);
            *(ushort4*)(hbf + hb + j0) = hv;
            if (q == 0) {
                a_src[(size_t)node * 8 + jt] = ps;
                a_dst[(size_t)node * 8 + jt] = pd;
            }
        }
    }
}

// ---- K6: per-node fused attn+aggregate+selfloop+LN+ReLU -----------------
// Barrier-free, LDS-free. 4 waves/block, 1 node/wave. 16-lane group owns
// 2 edges/iteration (6 independent loads in flight). Shuffle epilogue.
__global__ __launch_bounds__(256) void k_node(const int* __restrict__ tmp,
                                              const int* __restrict__ bscan,
                                              const int2* __restrict__ erec,
                                              const float* __restrict__ a_src,
                                              const float* __restrict__ a_dst,
                                              const float* __restrict__ w_e,
                                              const unsigned short* __restrict__ hbf,
                                              const float* __restrict__ x,
                                              const float* __restrict__ bias,
                                              const float* __restrict__ gamma,
                                              const float* __restrict__ beta,
                                              float* __restrict__ out, int N, int E) {
    int wv = threadIdx.x >> 6;
    int lane = threadIdx.x & 63;
    int n = blockIdx.x * 4 + wv;
    if (n >= N) return;
    int r0 = tmp[n] + bscan[n >> 10];
    int r1 = (n + 1 < N) ? (tmp[n + 1] + bscan[(n + 1) >> 10]) : E;
    int sub = lane >> 4;        // which of 4 concurrent edge-pairs
    int colg = lane & 15;       // col group: cols colg*8 .. colg*8+7
    int wh = colg >> 1;         // head of this col group
    float ad_h = a_dst[(size_t)n * 8 + wh];
    float we_h = w_e[wh];

    float acc[8];
#pragma unroll
    for (int j = 0; j < 8; j++) acc[j] = 0.f;
    float wsum = 0.f, suma = 0.f;

    for (int e = r0 + (sub << 1); e < r1; e += 8) {
        int2 rec0 = erec[e];
        bool m1 = (e + 1) < r1;
        int2 rec1 = m1 ? erec[e + 1] : rec0;
        int s0 = rec0.x, s1 = rec1.x;
        float ae0 = __int_as_float(rec0.y);
        float ae1 = __int_as_float(rec1.y);
        bf8 hv0 = *(const bf8*)(hbf + (size_t)s0 * HID + colg * 8);
        bf8 hv1 = *(const bf8*)(hbf + (size_t)s1 * HID + colg * 8);
        float as0 = a_src[(size_t)s0 * 8 + wh];
        float as1 = a_src[(size_t)s1 * 8 + wh];
        float v0 = as0 + ad_h + ae0 * we_h;
        float v1 = as1 + ad_h + ae1 * we_h;
        v0 = v0 > 0.f ? v0 : 0.2f * v0;
        v1 = v1 > 0.f ? v1 : 0.2f * v1;
        float w0 = __expf(v0);
        float w1 = m1 ? __expf(v1) : 0.f;
        wsum += w0 + w1;
        if (colg == 0) suma += ae0 + (m1 ? ae1 : 0.f);
#pragma unroll
        for (int j = 0; j < 8; j++) {
            acc[j] = fmaf(w0, bf2f((unsigned short)hv0[j]), acc[j]);
            acc[j] = fmaf(w1, bf2f((unsigned short)hv1[j]), acc[j]);
        }
    }

    // fold the 4 sub replicas
#pragma unroll
    for (int j = 0; j < 8; j++) {
        acc[j] += __shfl_xor(acc[j], 16, 64);
        acc[j] += __shfl_xor(acc[j], 32, 64);
    }
    wsum += __shfl_xor(wsum, 16, 64);
    wsum += __shfl_xor(wsum, 32, 64);
    suma += __shfl_xor(suma, 16, 64);
    suma += __shfl_xor(suma, 32, 64);

    // redistribute to 2-cols/lane: dest lane L pulls from ((L&3)<<4)|(L>>2)
    float accA = sub == 0 ? acc[0] : sub == 1 ? acc[2] : sub == 2 ? acc[4] : acc[6];
    float accB = sub == 0 ? acc[1] : sub == 1 ? acc[3] : sub == 2 ? acc[5] : acc[7];
    int srcL = ((lane & 3) << 4) | (lane >> 2);
    float a0 = __shfl(accA, srcL, 64);
    float a1 = __shfl(accB, srcL, 64);
    int head = lane >> 3;
    float denom = __shfl(wsum, head << 1, 64);
    float sa = __shfl(suma, 0, 64);

    // self-loop (fill_value='mean') + softmax finalize
    int deg = r1 - r0;
    float la = sa / fmaxf((float)deg, 1.0f);
    float adh = a_dst[(size_t)n * 8 + head];
    float weh = w_e[head];
    float vs = a_src[(size_t)n * 8 + head] + adh + la * weh;
    vs = vs > 0.f ? vs : 0.2f * vs;
    float exs = __expf(vs);
    size_t bx = (size_t)n * HID;
    ushort2 hs = *(const ushort2*)(hbf + bx + 2 * lane);
    a0 = fmaf(exs, bf2f(hs.x), a0);
    a1 = fmaf(exs, bf2f(hs.y), a1);
    float inv = 1.f / (denom + exs + 1e-16f);

    // residual + LayerNorm + ReLU
    float2 xv = *(const float2*)(x + bx + 2 * lane);
    float2 bv = *(const float2*)(bias + 2 * lane);
    float y0 = a0 * inv + bv.x + xv.x;
    float y1 = a1 * inv + bv.y + xv.y;
    float ss = y0 + y1, sq = y0 * y0 + y1 * y1;
#pragma unroll
    for (int off = 32; off; off >>= 1) {
        ss += __shfl_xor(ss, off, 64);
        sq += __shfl_xor(sq, off, 64);
    }
    float mu = ss * (1.f / 128.f);
    float var = sq * (1.f / 128.f) - mu * mu;
    float r = rsqrtf(fmaxf(var, 0.f) + 1e-5f);
    float2 gv = *(const float2*)(gamma + 2 * lane);
    float2 tv = *(const float2*)(beta + 2 * lane);
    float o0 = (y0 - mu) * r * gv.x + tv.x;
    float o1 = (y1 - mu) * r * gv.y + tv.y;
    float2 ov = make_float2(fmaxf(o0, 0.f), fmaxf(o1, 0.f));
    *(float2*)(out + bx + 2 * lane) = ov;
}

extern "C" void kernel_launch(void* const* d_in, const int* in_sizes, int n_in,
                              void* d_out, int out_size, void* d_ws, size_t ws_size,
                              hipStream_t stream) {
    const float* x        = (const float*)d_in[0];
    const int*   ei       = (const int*)d_in[1];
    const float* eattr    = (const float*)d_in[2];
    const float* W        = (const float*)d_in[3];
    const float* att_src  = (const float*)d_in[4];
    const float* att_dst  = (const float*)d_in[5];
    const float* w_edge   = (const float*)d_in[6];
    const float* att_edge = (const float*)d_in[7];
    const float* bias     = (const float*)d_in[8];
    const float* gamma    = (const float*)d_in[9];
    const float* beta     = (const float*)d_in[10];

    int N = in_sizes[0] / HID;
    int E = in_sizes[2];
    const int* src = ei;
    const int* dst = ei + E;
    float* out = (float*)d_out;

    int nbkt = (N + BKT - 1) / BKT;        // 391

    char* ws = (char*)d_ws;
    size_t off = 0;
    auto alloc = [&](size_t bytes) { char* p = ws + off; off += (bytes + 255) & ~255ull; return p; };
    unsigned short* hbf = (unsigned short*)alloc((size_t)N * HID * 2);
    unsigned short* Wt  = (unsigned short*)alloc((size_t)HID * HID * 2);
    float* a_src   = (float*)alloc((size_t)N * 8 * 4);
    float* a_dst   = (float*)alloc((size_t)N * 8 * 4);
    int2*  erec    = (int2*) alloc((size_t)E * 8);
    int2*  erec1   = (int2*) alloc((size_t)E * 8);
    int*   deg     = (int*)  alloc((size_t)N * 4);
    int*   tmp     = (int*)  alloc((size_t)N * 4);
    int*   bcur    = (int*)  alloc((size_t)nbkt * 4);
    int*   bsum    = (int*)  alloc(128 * 4);
    int*   bscan   = (int*)  alloc(128 * 4);
    float* w_e     = (float*)alloc(8 * 4);

    int nbA = (N + 1023) / 1024;           // 98 scan blocks
    int scatB = 512;
    int perS = (E + scatB - 1) / scatB;    // 3125

    k_tw<<<512, 256, 0, stream>>>(W, Wt, deg, bcur, N, nbkt);
    k_deg<<<2048, 256, 0, stream>>>(dst, deg, E);
    kscanA<<<nbA, 256, 0, stream>>>(deg, tmp, bsum, N);
    kscanB<<<1, 128, 0, stream>>>(bsum, bscan, nbA, w_edge, att_edge, w_e);
    k_scat2<<<scatB, 256, 0, stream>>>(src, dst, eattr, tmp, bscan, bcur, erec1, E, perS, nbkt);
    k_bin2<<<nbkt, 256, 0, stream>>>(tmp, bscan, erec1, erec, N, E, nbkt);
    k_gemm<<<(N + 63) / 64, 256, 0, stream>>>(x, Wt, att_src, att_dst, hbf, a_src, a_dst, N);
    k_node<<<(N + 3) / 4, 256, 0, stream>>>(tmp, bscan, erec, a_src, a_dst, w_e, hbf, x,
                                            bias, gamma, beta, out, N, E);
}

// Round 6
// 321.054 us; speedup vs baseline: 1.2511x; 1.1350x over previous
//
#include <hip/hip_runtime.h>
#include <math.h>

#define HID 128
#define HEADS 8
#define CDIM 16
#define BKT 256      // nodes per bucket

typedef short bf8 __attribute__((ext_vector_type(8)));
typedef float f32x4 __attribute__((ext_vector_type(4)));

__device__ __forceinline__ unsigned short f2bf(float f) {
    unsigned u = __float_as_uint(f);
    unsigned r = (u + 0x7fffu + ((u >> 16) & 1u)) >> 16;
    return (unsigned short)r;
}
__device__ __forceinline__ float bf2f(unsigned short u) {
    return __uint_as_float(((unsigned)u) << 16);
}

// ---- P0: Wt[j][k] = bf16(W[k][j]) + zero btot/bcur ---------------------
__global__ __launch_bounds__(256) void k_tw(const float* __restrict__ W,
                                            unsigned short* __restrict__ Wt,
                                            int* __restrict__ btot,
                                            int* __restrict__ bcur, int nbkt) {
    int idx = blockIdx.x * 256 + threadIdx.x;   // 64 blocks = 16384 threads
    if (idx < HID * HID) {
        int j = idx >> 7, k = idx & 127;
        Wt[idx] = f2bf(W[k * HID + j]);
    }
    if (idx < nbkt) { btot[idx] = 0; bcur[idx] = 0; }
}

// ---- P1: bucket totals via LDS histogram + one atomicAdd per bucket -----
__global__ __launch_bounds__(256) void k_hist(const int* __restrict__ dst,
                                              int* __restrict__ btot,
                                              int E, int per, int nbkt) {
    __shared__ int h[512];
    int t = threadIdx.x;
    for (int b = t; b < nbkt; b += 256) h[b] = 0;
    __syncthreads();
    int b0 = blockIdx.x * per;
    int b1 = min(b0 + per, E);
    for (int e = b0 + t; e < b1; e += 256)
        atomicAdd(&h[dst[e] >> 8], 1);
    __syncthreads();
    for (int b = t; b < nbkt; b += 256)
        if (h[b]) atomicAdd(&btot[b], h[b]);
}

// ---- P2: single-block scan of bucket totals -> bbase[nbkt+1]; + w_e -----
__global__ __launch_bounds__(512) void k_scan(const int* __restrict__ btot,
                                              int* __restrict__ bbase, int nbkt,
                                              const float* __restrict__ w_edge,
                                              const float* __restrict__ att_edge,
                                              float* __restrict__ w_e) {
    __shared__ int lds[512];
    int t = threadIdx.x;
    if (t < HEADS) {
        float s = 0.f;
        for (int c = 0; c < CDIM; c++) s += w_edge[t * CDIM + c] * att_edge[t * CDIM + c];
        w_e[t] = s;
    }
    lds[t] = (t < nbkt) ? btot[t] : 0;
    __syncthreads();
    for (int off = 1; off < 512; off <<= 1) {
        int xv = (t >= off) ? lds[t - off] : 0;
        __syncthreads();
        lds[t] += xv;
        __syncthreads();
    }
    if (t < nbkt) bbase[t] = (t > 0) ? lds[t - 1] : 0;
    if (t == nbkt) bbase[t] = lds[nbkt - 1];
}

// ---- MID: heterogeneous grid: [0,scatB) = scatter, rest = GEMM ----------
// Scatter: LDS hist + one chunk-reserve atomic per (block,bucket), then
// bucket-local sequential writes into erec1. Record = ((src<<8)|(d&255), ea).
// GEMM: h = x@W via MFMA (bf16 in, fp32 acc) + a_src/a_dst epilogue.
__global__ __launch_bounds__(256) void k_mid(const float* __restrict__ x,
                                             const unsigned short* __restrict__ Wt,
                                             const float* __restrict__ att_src,
                                             const float* __restrict__ att_dst,
                                             unsigned short* __restrict__ hbf,
                                             float* __restrict__ a_src,
                                             float* __restrict__ a_dst,
                                             const int* __restrict__ src,
                                             const int* __restrict__ dst,
                                             const float* __restrict__ eattr,
                                             const int* __restrict__ bbase,
                                             int* __restrict__ bcur,
                                             int2* __restrict__ erec1,
                                             int N, int E, int per, int nbkt,
                                             int scatB) {
    if ((int)blockIdx.x < scatB) {
        // ---- scatter body ----
        __shared__ int h[512];
        __shared__ int cur[512];
        int t = threadIdx.x;
        for (int b = t; b < nbkt; b += 256) h[b] = 0;
        __syncthreads();
        int b0 = blockIdx.x * per;
        int b1 = min(b0 + per, E);
        for (int e = b0 + t; e < b1; e += 256)
            atomicAdd(&h[dst[e] >> 8], 1);
        __syncthreads();
        for (int b = t; b < nbkt; b += 256) {
            int c = h[b];
            int base = bbase[b];
            if (c) base += atomicAdd(&bcur[b], c);
            cur[b] = base;
        }
        __syncthreads();
        for (int e = b0 + t; e < b1; e += 256) {
            int d = dst[e];
            int pos = atomicAdd(&cur[d >> 8], 1);
            erec1[pos] = make_int2((src[e] << 8) | (d & 255), __float_as_int(eattr[e]));
        }
        return;
    }
    // ---- GEMM body ----
    int bid = blockIdx.x - scatB;
    int tid = threadIdx.x;
    int wv = tid >> 6, lane = tid & 63;
    int nloc = lane & 15, q = lane >> 4;
    int node = bid * 64 + wv * 16 + nloc;
    int nc = min(node, N - 1);
    const float* xp = x + (size_t)nc * HID + q * 8;
    const unsigned short* wp = Wt + nloc * HID + q * 8; // A row j = jt*16 + nloc
    f32x4 acc[8];
#pragma unroll
    for (int i = 0; i < 8; i++) acc[i] = (f32x4){0.f, 0.f, 0.f, 0.f};
#pragma unroll
    for (int ch = 0; ch < 4; ch++) {
        float4 xv0 = *(const float4*)(xp + ch * 32);
        float4 xv1 = *(const float4*)(xp + ch * 32 + 4);
        bf8 bfrag;
        bfrag[0] = (short)f2bf(xv0.x); bfrag[1] = (short)f2bf(xv0.y);
        bfrag[2] = (short)f2bf(xv0.z); bfrag[3] = (short)f2bf(xv0.w);
        bfrag[4] = (short)f2bf(xv1.x); bfrag[5] = (short)f2bf(xv1.y);
        bfrag[6] = (short)f2bf(xv1.z); bfrag[7] = (short)f2bf(xv1.w);
#pragma unroll
        for (int jt = 0; jt < 8; jt++) {
            bf8 afrag = *(const bf8*)(wp + (size_t)jt * 16 * HID + ch * 32);
            acc[jt] = __builtin_amdgcn_mfma_f32_16x16x32_bf16(afrag, bfrag, acc[jt], 0, 0, 0);
        }
    }
    bool ok = node < N;
    size_t hb = (size_t)nc * HID;
#pragma unroll
    for (int jt = 0; jt < 8; jt++) {
        int j0 = jt * 16 + q * 4;
        float4 as4 = *(const float4*)(att_src + j0);
        float4 ad4 = *(const float4*)(att_dst + j0);
        f32x4 a = acc[jt];
        float ps = a[0] * as4.x + a[1] * as4.y + a[2] * as4.z + a[3] * as4.w;
        float pd = a[0] * ad4.x + a[1] * ad4.y + a[2] * ad4.z + a[3] * ad4.w;
        ps += __shfl_xor(ps, 16, 64); ps += __shfl_xor(ps, 32, 64);
        pd += __shfl_xor(pd, 16, 64); pd += __shfl_xor(pd, 32, 64);
        if (ok) {
            ushort4 hv;
            hv.x = f2bf(a[0]); hv.y = f2bf(a[1]); hv.z = f2bf(a[2]); hv.w = f2bf(a[3]);
            *(ushort4*)(hbf + hb + j0) = hv;
            if (q == 0) {
                a_src[(size_t)node * 8 + jt] = ps;
                a_dst[(size_t)node * 8 + jt] = pd;
            }
        }
    }
}

// ---- S2: fine bin within bucket: LDS hist+scan -> row_ptr, re-scatter ---
__global__ __launch_bounds__(256) void k_bin2(const int* __restrict__ bbase,
                                              const int2* __restrict__ erec1,
                                              int2* __restrict__ erec,
                                              int* __restrict__ row_ptr,
                                              int N, int nbkt) {
    __shared__ int h[256];
    __shared__ int s[256];
    __shared__ int cur[256];
    int b = blockIdx.x, t = threadIdx.x;
    int base = bbase[b], end = bbase[b + 1];
    h[t] = 0;
    __syncthreads();
    for (int e = base + t; e < end; e += 256)
        atomicAdd(&h[erec1[e].x & 255], 1);
    __syncthreads();
    s[t] = h[t];
    __syncthreads();
    for (int off = 1; off < 256; off <<= 1) {
        int v = (t >= off) ? s[t - off] : 0;
        __syncthreads();
        s[t] += v;
        __syncthreads();
    }
    int exc = (t > 0) ? s[t - 1] : 0;
    int node = (b << 8) + t;
    if (node <= N) row_ptr[node] = base + exc;
    cur[t] = base + exc;
    __syncthreads();
    for (int e = base + t; e < end; e += 256) {
        int2 r = erec1[e];
        int pos = atomicAdd(&cur[r.x & 255], 1);
        erec[pos] = make_int2(r.x >> 8, r.y);
    }
}

// ---- K6: per-node fused attn+aggregate+selfloop+LN+ReLU -----------------
// Barrier-free, LDS-free. 4 waves/block, 1 node/wave. 16-lane group owns
// 2 edges/iteration (6 independent loads in flight). Shuffle epilogue.
__global__ __launch_bounds__(256) void k_node(const int* __restrict__ row_ptr,
                                              const int2* __restrict__ erec,
                                              const float* __restrict__ a_src,
                                              const float* __restrict__ a_dst,
                                              const float* __restrict__ w_e,
                                              const unsigned short* __restrict__ hbf,
                                              const float* __restrict__ x,
                                              const float* __restrict__ bias,
                                              const float* __restrict__ gamma,
                                              const float* __restrict__ beta,
                                              float* __restrict__ out, int N) {
    int wv = threadIdx.x >> 6;
    int lane = threadIdx.x & 63;
    int n = blockIdx.x * 4 + wv;
    if (n >= N) return;
    int r0 = row_ptr[n], r1 = row_ptr[n + 1];
    int sub = lane >> 4;        // which of 4 concurrent edge-pairs
    int colg = lane & 15;       // col group: cols colg*8 .. colg*8+7
    int wh = colg >> 1;         // head of this col group
    float ad_h = a_dst[(size_t)n * 8 + wh];
    float we_h = w_e[wh];

    float acc[8];
#pragma unroll
    for (int j = 0; j < 8; j++) acc[j] = 0.f;
    float wsum = 0.f, suma = 0.f;

    for (int e = r0 + (sub << 1); e < r1; e += 8) {
        int2 rec0 = erec[e];
        bool m1 = (e + 1) < r1;
        int2 rec1 = m1 ? erec[e + 1] : rec0;
        int s0 = rec0.x, s1 = rec1.x;
        float ae0 = __int_as_float(rec0.y);
        float ae1 = __int_as_float(rec1.y);
        bf8 hv0 = *(const bf8*)(hbf + (size_t)s0 * HID + colg * 8);
        bf8 hv1 = *(const bf8*)(hbf + (size_t)s1 * HID + colg * 8);
        float as0 = a_src[(size_t)s0 * 8 + wh];
        float as1 = a_src[(size_t)s1 * 8 + wh];
        float v0 = as0 + ad_h + ae0 * we_h;
        float v1 = as1 + ad_h + ae1 * we_h;
        v0 = v0 > 0.f ? v0 : 0.2f * v0;
        v1 = v1 > 0.f ? v1 : 0.2f * v1;
        float w0 = __expf(v0);
        float w1 = m1 ? __expf(v1) : 0.f;
        wsum += w0 + w1;
        if (colg == 0) suma += ae0 + (m1 ? ae1 : 0.f);
#pragma unroll
        for (int j = 0; j < 8; j++) {
            acc[j] = fmaf(w0, bf2f((unsigned short)hv0[j]), acc[j]);
            acc[j] = fmaf(w1, bf2f((unsigned short)hv1[j]), acc[j]);
        }
    }

    // fold the 4 sub replicas
#pragma unroll
    for (int j = 0; j < 8; j++) {
        acc[j] += __shfl_xor(acc[j], 16, 64);
        acc[j] += __shfl_xor(acc[j], 32, 64);
    }
    wsum += __shfl_xor(wsum, 16, 64);
    wsum += __shfl_xor(wsum, 32, 64);
    suma += __shfl_xor(suma, 16, 64);
    suma += __shfl_xor(suma, 32, 64);

    // redistribute to 2-cols/lane: dest lane L pulls from ((L&3)<<4)|(L>>2)
    float accA = sub == 0 ? acc[0] : sub == 1 ? acc[2] : sub == 2 ? acc[4] : acc[6];
    float accB = sub == 0 ? acc[1] : sub == 1 ? acc[3] : sub == 2 ? acc[5] : acc[7];
    int srcL = ((lane & 3) << 4) | (lane >> 2);
    float a0 = __shfl(accA, srcL, 64);
    float a1 = __shfl(accB, srcL, 64);
    int head = lane >> 3;
    float denom = __shfl(wsum, head << 1, 64);
    float sa = __shfl(suma, 0, 64);

    // self-loop (fill_value='mean') + softmax finalize
    int deg = r1 - r0;
    float la = sa / fmaxf((float)deg, 1.0f);
    float adh = a_dst[(size_t)n * 8 + head];
    float weh = w_e[head];
    float vs = a_src[(size_t)n * 8 + head] + adh + la * weh;
    vs = vs > 0.f ? vs : 0.2f * vs;
    float exs = __expf(vs);
    size_t bx = (size_t)n * HID;
    ushort2 hs = *(const ushort2*)(hbf + bx + 2 * lane);
    a0 = fmaf(exs, bf2f(hs.x), a0);
    a1 = fmaf(exs, bf2f(hs.y), a1);
    float inv = 1.f / (denom + exs + 1e-16f);

    // residual + LayerNorm + ReLU
    float2 xv = *(const float2*)(x + bx + 2 * lane);
    float2 bv = *(const float2*)(bias + 2 * lane);
    float y0 = a0 * inv + bv.x + xv.x;
    float y1 = a1 * inv + bv.y + xv.y;
    float ss = y0 + y1, sq = y0 * y0 + y1 * y1;
#pragma unroll
    for (int off = 32; off; off >>= 1) {
        ss += __shfl_xor(ss, off, 64);
        sq += __shfl_xor(sq, off, 64);
    }
    float mu = ss * (1.f / 128.f);
    float var = sq * (1.f / 128.f) - mu * mu;
    float r = rsqrtf(fmaxf(var, 0.f) + 1e-5f);
    float2 gv = *(const float2*)(gamma + 2 * lane);
    float2 tv = *(const float2*)(beta + 2 * lane);
    float o0 = (y0 - mu) * r * gv.x + tv.x;
    float o1 = (y1 - mu) * r * gv.y + tv.y;
    float2 ov = make_float2(fmaxf(o0, 0.f), fmaxf(o1, 0.f));
    *(float2*)(out + bx + 2 * lane) = ov;
}

extern "C" void kernel_launch(void* const* d_in, const int* in_sizes, int n_in,
                              void* d_out, int out_size, void* d_ws, size_t ws_size,
                              hipStream_t stream) {
    const float* x        = (const float*)d_in[0];
    const int*   ei       = (const int*)d_in[1];
    const float* eattr    = (const float*)d_in[2];
    const float* W        = (const float*)d_in[3];
    const float* att_src  = (const float*)d_in[4];
    const float* att_dst  = (const float*)d_in[5];
    const float* w_edge   = (const float*)d_in[6];
    const float* att_edge = (const float*)d_in[7];
    const float* bias     = (const float*)d_in[8];
    const float* gamma    = (const float*)d_in[9];
    const float* beta     = (const float*)d_in[10];

    int N = in_sizes[0] / HID;
    int E = in_sizes[2];
    const int* src = ei;
    const int* dst = ei + E;
    float* out = (float*)d_out;

    int nbkt = (N + BKT - 1) / BKT;        // 391

    char* ws = (char*)d_ws;
    size_t off = 0;
    auto alloc = [&](size_t bytes) { char* p = ws + off; off += (bytes + 255) & ~255ull; return p; };
    unsigned short* hbf = (unsigned short*)alloc((size_t)N * HID * 2);
    unsigned short* Wt  = (unsigned short*)alloc((size_t)HID * HID * 2);
    float* a_src   = (float*)alloc((size_t)N * 8 * 4);
    float* a_dst   = (float*)alloc((size_t)N * 8 * 4);
    int2*  erec    = (int2*) alloc((size_t)E * 8);
    int2*  erec1   = (int2*) alloc((size_t)E * 8);
    int*   btot    = (int*)  alloc(512 * 4);
    int*   bcur    = (int*)  alloc(512 * 4);
    int*   bbase   = (int*)  alloc(520 * 4);
    int*   row_ptr = (int*)  alloc((size_t)(N + 1) * 4);
    float* w_e     = (float*)alloc(8 * 4);

    int histB = 512;
    int per = (E + histB - 1) / histB;     // 3125
    int scatB = 512;
    int gemmB = (N + 63) / 64;             // 1563

    k_tw<<<64, 256, 0, stream>>>(W, Wt, btot, bcur, nbkt);
    k_hist<<<histB, 256, 0, stream>>>(dst, btot, E, per, nbkt);
    k_scan<<<1, 512, 0, stream>>>(btot, bbase, nbkt, w_edge, att_edge, w_e);
    k_mid<<<scatB + gemmB, 256, 0, stream>>>(
        x, Wt, att_src, att_dst, hbf, a_src, a_dst,
        src, dst, eattr, bbase, bcur, erec1, N, E, per, nbkt, scatB);
    k_bin2<<<nbkt, 256, 0, stream>>>(bbase, erec1, erec, row_ptr, N, nbkt);
    k_node<<<(N + 3) / 4, 256, 0, stream>>>(row_ptr, erec, a_src, a_dst, w_e, hbf, x,
                                            bias, gamma, beta, out, N);
}